// Round 8
// baseline (254.835 us; speedup 1.0000x reference)
//
#include <hip/hip_runtime.h>
#include <hip/hip_bf16.h>
#include <stdint.h>

// Problem constants (B=8192, I=512, H=1024, D=8)
#define B_N 8192
#define I_N 512
#define H_N 1024

typedef __bf16 bf16x8 __attribute__((ext_vector_type(8)));
typedef float f32x4 __attribute__((ext_vector_type(4)));
typedef unsigned short u16;
typedef unsigned int u32;

__device__ inline void gld_lds16(const void* g, void* l) {
  __builtin_amdgcn_global_load_lds(
      (const __attribute__((address_space(1))) unsigned int*)g,
      (__attribute__((address_space(3))) unsigned int*)l,
      16, 0, 0);
}

__device__ inline u16 f2bf(float f) {
  __hip_bfloat16 h = __float2bfloat16(f);
  return __builtin_bit_cast(u16, h);
}

__device__ inline float bf2f(u16 b) {
  unsigned int u = ((unsigned int)b) << 16;
  return __builtin_bit_cast(float, u);
}

__device__ inline u32 pack2bf(float lo, float hi) {
  return (u32)f2bf(lo) | ((u32)f2bf(hi) << 16);
}

// ---------------- prep: fused bf16 conversion (x, Wih, Whh) + hidden decay ----
__global__ void prep(const float* __restrict__ x, const float* __restrict__ wih,
                     const float* __restrict__ whh, const float* __restrict__ h,
                     const float* __restrict__ delta, const float* __restrict__ wg,
                     const float* __restrict__ bg, u16* __restrict__ xb,
                     u16* __restrict__ wihb, u16* __restrict__ whhb,
                     u16* __restrict__ hdec) {
  const int b = blockIdx.x;
  if (b < 4352) {
    const float* src; u16* dst; int base;
    if (b < 2048)      { src = x;   dst = xb;   base = b; }
    else if (b < 2816) { src = wih; dst = wihb; base = b - 2048; }
    else               { src = whh; dst = whhb; base = b - 2816; }
    const int i = (base * 256 + (int)threadIdx.x) * 8;
    float4 a0 = *(const float4*)(src + i);
    float4 a1 = *(const float4*)(src + i + 4);
    union { u16 u[8]; float4 v; } pk;
    pk.u[0] = f2bf(a0.x); pk.u[1] = f2bf(a0.y); pk.u[2] = f2bf(a0.z); pk.u[3] = f2bf(a0.w);
    pk.u[4] = f2bf(a1.x); pk.u[5] = f2bf(a1.y); pk.u[6] = f2bf(a1.z); pk.u[7] = f2bf(a1.w);
    *(float4*)(dst + i) = pk.v;
  } else {
    const int idx8 = (b - 4352) * 2048 + (int)threadIdx.x * 8;  // over B*H, 8-aligned
    const int bb = idx8 >> 10;   // H_N = 1024
    const int j  = idx8 & 1023;
    const float4* d4 = (const float4*)(delta + (size_t)bb * 8);
    const float4 d0 = d4[0], d1 = d4[1];
    const float4* h4 = (const float4*)(h + idx8);
    const float4 h0 = h4[0], h1 = h4[1];
    const float4* b4 = (const float4*)(bg + j);
    const float4 bg0 = b4[0], bg1 = b4[1];
    const float hv[8]  = {h0.x, h0.y, h0.z, h0.w, h1.x, h1.y, h1.z, h1.w};
    const float bgv[8] = {bg0.x, bg0.y, bg0.z, bg0.w, bg1.x, bg1.y, bg1.z, bg1.w};
    union { u16 u[8]; float4 v; } pk;
#pragma unroll
    for (int t = 0; t < 8; ++t) {
      const float4* w4 = (const float4*)(wg + (size_t)(j + t) * 8);
      const float4 w0 = w4[0], w1 = w4[1];
      float s = d0.x*w0.x + d0.y*w0.y + d0.z*w0.z + d0.w*w0.w
              + d1.x*w1.x + d1.y*w1.y + d1.z*w1.z + d1.w*w1.w + bgv[t];
      s = s > 0.0f ? s : 0.0f;
      pk.u[t] = f2bf(__expf(-s) * hv[t]);
    }
    *(float4*)(hdec + idx8) = pk.v;
  }
}

// ---------- fused GRU GEMM — R0 structure, BK=32, 20 KB LDS (occupancy probe) ----
// Ledger: R0 BK=64/40KB = 102.5us (MfmaUtil 31%, Occ ~20% = ~2 blocks/CU);
// every schedule restructure regressed (R2 126.9, R3 168, R4 128.5, R6 114.9,
// R7 BK=128/80KB 108.8 at the SAME ~20% occupancy as 40KB -> residency is
// capped at 2 blocks/CU by something other than the nominal LDS/VGPR math
// (suspect LDS allocation granularity).
// THIS round: BK=32 -> LDS 20 KB/block (8 KB A + 12 KB W), single-buffer,
// otherwise byte-identical R0 body. If the cap was LDS granularity, 4 blocks/CU
// become co-resident (VGPR 128 caps at 4) and the per-K-step vmcnt(0) drain at
// __syncthreads overlaps 4-way via TLP — the mechanism (m114) that all explicit
// pipelining attempts failed to beat.
// Same linear k order -> MFMA accumulation order identical -> absmax 0.015625.
__global__ __launch_bounds__(256, 2) void gru_gemm(
    const u16* __restrict__ xb,    // [B, I] bf16
    const u16* __restrict__ hdec,  // [B, H] bf16 (decayed h)
    const u16* __restrict__ wihb,  // [3H, I] bf16
    const u16* __restrict__ whhb,  // [3H, H] bf16
    const float* __restrict__ bih, // [3H]
    const float* __restrict__ bhh, // [3H]
    float* __restrict__ out)       // [B, H] f32
{
  __shared__ __attribute__((aligned(16))) u16 As[128 * 32];     // 8 KB
  __shared__ __attribute__((aligned(16))) u16 Ws[3][64 * 32];   // 12 KB

  const int tid  = threadIdx.x;
  const int lane = tid & 63;
  const int wave = tid >> 6;
  const int wm = wave & 1;   // row half (64 rows each)
  const int wn = wave >> 1;  // col half (32 cols each)
  const int m0 = blockIdx.x * 128;
  const int j0 = blockIdx.y * 64;

  const int srow = tid >> 2;                              // 0..63 staging row
  const int sk   = (((tid & 3) ^ ((tid >> 3) & 3)) * 8);  // swizzled global chunk
  const int frow = lane & 15;                             // fragment row/col
  const int fkp  = (((lane >> 4) ^ ((frow >> 1) & 3)) * 8); // swizzled read offset

  f32x4 acc[3][4][2];
  u32 park[3][4][2][2];

#pragma unroll
  for (int g = 0; g < 3; ++g)
#pragma unroll
    for (int rb = 0; rb < 4; ++rb)
#pragma unroll
      for (int cb = 0; cb < 2; ++cb)
#pragma unroll
        for (int r = 0; r < 4; ++r) acc[g][rb][cb][r] = 0.0f;

#define GEMM_PASS(APTR, WPTR, LD, KTOT)                                         \
  for (int k0 = 0; k0 < (KTOT); k0 += 32) {                                     \
    _Pragma("unroll")                                                           \
    for (int o = 0; o < 2; ++o)                                                 \
      gld_lds16((APTR) + (size_t)(m0 + o * 64 + srow) * (LD) + k0 + sk,         \
                &As[o * 2048 + tid * 8]);                                       \
    _Pragma("unroll")                                                           \
    for (int g = 0; g < 3; ++g)                                                 \
      gld_lds16((WPTR) + (size_t)(g * H_N + j0 + srow) * (LD) + k0 + sk,        \
                &Ws[g][tid * 8]);                                               \
    __syncthreads();                                                            \
    {                                                                           \
      bf16x8 af[4];                                                             \
      _Pragma("unroll")                                                         \
      for (int rb = 0; rb < 4; ++rb)                                            \
        af[rb] = *(const bf16x8*)&As[(wm * 64 + rb * 16 + frow) * 32 + fkp];    \
      _Pragma("unroll")                                                         \
      for (int g = 0; g < 3; ++g) {                                             \
        _Pragma("unroll")                                                       \
        for (int cb = 0; cb < 2; ++cb) {                                        \
          bf16x8 wf = *(const bf16x8*)&Ws[g][(wn * 32 + cb * 16 + frow) * 32 + fkp]; \
          _Pragma("unroll")                                                     \
          for (int rb = 0; rb < 4; ++rb)                                        \
            acc[g][rb][cb] = __builtin_amdgcn_mfma_f32_16x16x32_bf16(           \
                af[rb], wf, acc[g][rb][cb], 0, 0, 0);                           \
        }                                                                       \
      }                                                                         \
    }                                                                           \
    __syncthreads();                                                            \
  }

  // ---- K-loop 1: x @ Wih^T (K = 512, 16 K-steps) ----
  GEMM_PASS(xb, wihb, I_N, I_N)

  // park ih gates as packed bf16, re-zero accs
#pragma unroll
  for (int g = 0; g < 3; ++g)
#pragma unroll
    for (int rb = 0; rb < 4; ++rb)
#pragma unroll
      for (int cb = 0; cb < 2; ++cb) {
        park[g][rb][cb][0] = pack2bf(acc[g][rb][cb][0], acc[g][rb][cb][1]);
        park[g][rb][cb][1] = pack2bf(acc[g][rb][cb][2], acc[g][rb][cb][3]);
#pragma unroll
        for (int r = 0; r < 4; ++r) acc[g][rb][cb][r] = 0.0f;
      }

  // ---- K-loop 2: hdec @ Whh^T (K = 1024, 32 K-steps) ----
  GEMM_PASS(hdec, whhb, H_N, H_N)

#undef GEMM_PASS

  // ---- epilogue: gates + output ----
  // C/D 16x16: col = lane&15, row = (lane>>4)*4 + reg
#pragma unroll
  for (int cb = 0; cb < 2; ++cb) {
    const int col = j0 + wn * 32 + cb * 16 + frow;
    const float b_ir = bih[col];
    const float b_iz = bih[H_N + col];
    const float b_in = bih[2 * H_N + col];
    const float b_hr = bhh[col];
    const float b_hz = bhh[H_N + col];
    const float b_hn = bhh[2 * H_N + col];
#pragma unroll
    for (int rb = 0; rb < 4; ++rb) {
      const int rbase = m0 + wm * 64 + rb * 16 + (lane >> 4) * 4;
#pragma unroll
      for (int r = 0; r < 4; ++r) {
        const int row = rbase + r;
        const int sh = (r & 1) * 16;
        float ir  = bf2f((u16)(park[0][rb][cb][r >> 1] >> sh)) + b_ir;
        float iz  = bf2f((u16)(park[1][rb][cb][r >> 1] >> sh)) + b_iz;
        float in_ = bf2f((u16)(park[2][rb][cb][r >> 1] >> sh)) + b_in;
        float hr = acc[0][rb][cb][r] + b_hr;
        float hz = acc[1][rb][cb][r] + b_hz;
        float hn = acc[2][rb][cb][r] + b_hn;
        float rg = 1.0f / (1.0f + __expf(-(ir + hr)));
        float zg = 1.0f / (1.0f + __expf(-(iz + hz)));
        float s  = in_ + rg * hn;
        float e  = __expf(2.0f * s);
        float ng = (e - 1.0f) / (e + 1.0f);   // tanh(s), stable both tails
        float hv = bf2f(hdec[(size_t)row * H_N + col]);
        out[(size_t)row * H_N + col] = ng + zg * (hv - ng);
      }
    }
  }
}

extern "C" void kernel_launch(void* const* d_in, const int* in_sizes, int n_in,
                              void* d_out, int out_size, void* d_ws, size_t ws_size,
                              hipStream_t stream) {
  const float* x     = (const float*)d_in[0];
  const float* delta = (const float*)d_in[1];
  const float* h     = (const float*)d_in[2];
  const float* wih   = (const float*)d_in[3];
  const float* whh   = (const float*)d_in[4];
  const float* bih   = (const float*)d_in[5];
  const float* bhh   = (const float*)d_in[6];
  const float* wg    = (const float*)d_in[7];
  const float* bg    = (const float*)d_in[8];
  float* out = (float*)d_out;

  char* ws = (char*)d_ws;
  u16* xb   = (u16*)(ws);                 // x bf16:   8192*512*2  =  8,388,608 B
  u16* hdec = (u16*)(ws + 8388608);       // hdec bf16:8192*1024*2 = 16,777,216 B
  u16* wihb = (u16*)(ws + 25165824);      // Wih bf16: 3072*512*2  =  3,145,728 B
  u16* whhb = (u16*)(ws + 28311552);      // Whh bf16: 3072*1024*2 =  6,291,456 B

  prep<<<8448, 256, 0, stream>>>(x, wih, whh, h, delta, wg, bg, xb, wihb, whhb, hdec);
  gru_gemm<<<dim3(B_N / 128, H_N / 64), 256, 0, stream>>>(xb, hdec, wihb, whhb, bih, bhh, out);
}